// Round 22
// baseline (68.225 us; speedup 1.0000x reference)
//
#include <hip/hip_runtime.h>
#include <hip/hip_bf16.h>

typedef float f32x4 __attribute__((ext_vector_type(4)));
typedef float f32x2 __attribute__((ext_vector_type(2)));
typedef short s16x8 __attribute__((ext_vector_type(8)));
typedef short s16x4 __attribute__((ext_vector_type(4)));

#define NB  4
#define NTQ 128
#define NTK 512
#define NH  1024
#define ECLAMP 3.0e4f   // keeps 4-way u-products < f32 max; tanh delta < 1e-9

__device__ __forceinline__ unsigned short f2bf(float x) {
    unsigned u = __builtin_bit_cast(unsigned, x);
    u += 0x7FFFu + ((u >> 16) & 1u);          // round-to-nearest-even
    return (unsigned short)(u >> 16);
}

#define K2E  2.8853900817779268f   // 2*log2(e): exp2(K2E*x) = e^{2x}

// async global->LDS 16B: linear LDS dest (wave base + lane*16), per-lane global src
#define GLD16(gp, lp) __builtin_amdgcn_global_load_lds( \
    (const __attribute__((address_space(1))) unsigned int*)(gp), \
    (__attribute__((address_space(3))) unsigned int*)(lp), 16, 0, 0)

// ---------------------------------------------------------------------------
// prep: blocks [0,640): bf16 copy Q|K (float4 coalesced).
// blocks [640,1664): 64x64 transpose-convert tiles: Wq->WqT, Wk->WkT, value->valT.
__global__ __launch_bounds__(256) void prep_kernel(
    const float* __restrict__ Q, const float* __restrict__ K,
    const float* __restrict__ Wq, const float* __restrict__ Wk,
    const float* __restrict__ value,
    short* __restrict__ Qb, short* __restrict__ Kb,
    short* __restrict__ WqT, short* __restrict__ WkT, short* __restrict__ valT)
{
    const int t = threadIdx.x, bx = blockIdx.x;
    if (bx < 640) {   // copy region: blocks [0,128) = Q, [128,640) = K
        const float* src; short* dst; size_t base;
        if (bx < 128) { src = Q; dst = Qb; base = (size_t)bx * 4096; }
        else          { src = K; dst = Kb; base = (size_t)(bx - 128) * 4096; }
        #pragma unroll
        for (int i = 0; i < 4; ++i) {
            const size_t off = base + (size_t)(i * 256 + t) * 4;
            const float4 vv = *(const float4*)(src + off);
            s16x4 o = { (short)f2bf(vv.x), (short)f2bf(vv.y),
                        (short)f2bf(vv.z), (short)f2bf(vv.w) };
            *(s16x4*)(dst + off) = o;
        }
        return;
    }
    // transpose region
    __shared__ float tile[64][65];
    const int i = bx - 640;
    const float* src; short* dst; int Cs, Rs, r0, c0;
    if (i < 256)      { src = Wq; dst = WqT; Cs = 1024; Rs = 1024; r0 = (i >> 4) * 64; c0 = (i & 15) * 64; }
    else if (i < 512) { const int j = i - 256; src = Wk; dst = WkT; Cs = 1024; Rs = 1024; r0 = (j >> 4) * 64; c0 = (j & 15) * 64; }
    else {
        const int j = i - 512, b = j >> 7, ti = j & 127;
        src = value + (size_t)b * 512 * 1024; dst = valT + (size_t)b * 1024 * 512;
        Cs = 1024; Rs = 512; r0 = (ti >> 4) * 64; c0 = (ti & 15) * 64;
    }
    {   // load 64x64 f32 tile, coalesced 256B/row
        const int c = (t & 15) * 4;
        #pragma unroll
        for (int it = 0; it < 4; ++it) {
            const int r = (t >> 4) + it * 16;
            const float4 vv = *(const float4*)(src + (size_t)(r0 + r) * Cs + c0 + c);
            tile[r][c + 0] = vv.x; tile[r][c + 1] = vv.y;
            tile[r][c + 2] = vv.z; tile[r][c + 3] = vv.w;
        }
    }
    __syncthreads();
    {   // write transposed: 128B per 16-lane group
        const int r = (t & 15) * 4;
        #pragma unroll
        for (int it = 0; it < 4; ++it) {
            const int c = (t >> 4) + it * 16;
            s16x4 o = { (short)f2bf(tile[r + 0][c]), (short)f2bf(tile[r + 1][c]),
                        (short)f2bf(tile[r + 2][c]), (short)f2bf(tile[r + 3][c]) };
            *(s16x4*)(dst + (size_t)(c0 + c) * Rs + r0 + r) = o;
        }
    }
}

// ---------------------------------------------------------------------------
// main GEMMs with epilogue exp (clamped at ECLAMP): swz blocks [0,64): Ea f32;
// [64,320): EbT[b][h][k] transposed, stored bf16.
// 128m x 64n tile, BK=64, dbuf LDS via global_load_lds, XOR-swizzled (rule #21).
__global__ __launch_bounds__(256) void mm_kernel(
    const short* __restrict__ Qb, const short* __restrict__ Kb,
    const short* __restrict__ WqT, const short* __restrict__ WkT,
    const float* __restrict__ bq,
    float* __restrict__ Ea_out, unsigned short* __restrict__ EbT)
{
    __shared__ short ldsA[2][128][64];   // 32 KB
    __shared__ short ldsB[2][64][64];    // 16 KB
    const int t = threadIdx.x;
    const int bx0 = blockIdx.x;
    const int bx = (bx0 & 7) * 40 + (bx0 >> 3);   // XCD-chunked swizzle
    const bool g1 = bx < 64;
    const short *A, *B; int m0, n0;
    if (g1) { A = Qb; B = WqT; m0 = (bx >> 4) * 128; n0 = (bx & 15) * 64; }
    else    { const int i = bx - 64; A = Kb; B = WkT; m0 = (i >> 4) * 128; n0 = (i & 15) * 64; }
    A += (size_t)m0 * 1024; B += (size_t)n0 * 1024;

    f32x4 acc[4][2];
    #pragma unroll
    for (int i = 0; i < 4; ++i)
        #pragma unroll
        for (int j = 0; j < 2; ++j) acc[i][j] = f32x4{0.f, 0.f, 0.f, 0.f};

    const int lane = t & 63, wid = t >> 6;
    const int wr = wid >> 1, wc = wid & 1;          // waves 2x2 over (64m,32n)
    const int fr = lane & 15, fko = (lane >> 4) * 16;   // byte offset in 128B row

    #define STAGE_MM(buf, k0) do {                                              \
        _Pragma("unroll")                                                       \
        for (int it = 0; it < 4; ++it) {                                        \
            const int idx = it * 256 + t;                                       \
            const int row = idx >> 3, c16 = idx & 7;                            \
            const int sc = c16 ^ (row & 7);                                     \
            GLD16(A + (size_t)row * 1024 + (k0) + sc * 8,                       \
                  &ldsA[buf][0][0] + idx * 8);                                  \
        }                                                                       \
        _Pragma("unroll")                                                       \
        for (int it = 0; it < 2; ++it) {                                        \
            const int idx = it * 256 + t;                                       \
            const int row = idx >> 3, c16 = idx & 7;                            \
            const int sc = c16 ^ (row & 7);                                     \
            GLD16(B + (size_t)row * 1024 + (k0) + sc * 8,                       \
                  &ldsB[buf][0][0] + idx * 8);                                  \
        }                                                                       \
    } while (0)

    #define COMPUTE_MM(buf) do {                                                \
        _Pragma("unroll")                                                       \
        for (int kk = 0; kk < 2; ++kk) {                                        \
            s16x8 af[4], bfv[2];                                                \
            _Pragma("unroll")                                                   \
            for (int i = 0; i < 4; ++i) {                                       \
                const int rowA = wr * 64 + i * 16 + fr;                         \
                int offA = rowA * 128 + kk * 64 + fko; offA ^= (rowA & 7) << 4; \
                af[i] = *(const s16x8*)((const char*)&ldsA[buf][0][0] + offA);  \
            }                                                                   \
            _Pragma("unroll")                                                   \
            for (int ni = 0; ni < 2; ++ni) {                                    \
                const int rowB = wc * 32 + ni * 16 + fr;                        \
                int offB = rowB * 128 + kk * 64 + fko; offB ^= (rowB & 7) << 4; \
                bfv[ni] = *(const s16x8*)((const char*)&ldsB[buf][0][0] + offB);\
            }                                                                   \
            _Pragma("unroll")                                                   \
            for (int mi = 0; mi < 4; ++mi)                                      \
                _Pragma("unroll")                                               \
                for (int ni = 0; ni < 2; ++ni)                                  \
                    acc[mi][ni] = __builtin_amdgcn_mfma_f32_16x16x32_bf16(      \
                                      af[mi], bfv[ni], acc[mi][ni], 0, 0, 0);   \
        }                                                                       \
    } while (0)

    STAGE_MM(0, 0);
    __syncthreads();
    int cur = 0;
    for (int s = 0; s < 15; ++s) {
        STAGE_MM(cur ^ 1, (s + 1) * 64);
        COMPUTE_MM(cur);
        __syncthreads();
        cur ^= 1;
    }
    COMPUTE_MM(cur);

    // D layout: col = lane&15, row = (lane>>4)*4 + reg
    const int row0 = (lane >> 4) * 4;
    if (g1) {
        #pragma unroll
        for (int ni = 0; ni < 2; ++ni) {
            const int n = n0 + wc * 32 + ni * 16 + fr;
            const float bias = bq[n];
            #pragma unroll
            for (int mi = 0; mi < 4; ++mi) {
                const int m = m0 + wr * 64 + mi * 16 + row0;
                #pragma unroll
                for (int j = 0; j < 4; ++j)
                    Ea_out[(size_t)(m + j) * 1024 + n] =
                        fminf(__builtin_amdgcn_exp2f(K2E * (acc[mi][ni][j] + bias)), ECLAMP);
            }
        }
    } else {
        #pragma unroll
        for (int mi = 0; mi < 4; ++mi) {
            const int m = m0 + wr * 64 + mi * 16 + row0;
            const int b = m >> 9, kk = m & 511;
            #pragma unroll
            for (int ni = 0; ni < 2; ++ni) {
                const int n = n0 + wc * 32 + ni * 16 + fr;
                s16x4 ev;
                #pragma unroll
                for (int j = 0; j < 4; ++j)
                    ev[j] = (short)f2bf(fminf(__builtin_amdgcn_exp2f(K2E * acc[mi][ni][j]), ECLAMP));
                *(s16x4*)&EbT[((size_t)b * 1024 + n) * 512 + kk] = ev;
            }
        }
    }
    #undef STAGE_MM
    #undef COMPUTE_MM
}

// ---------------------------------------------------------------------------
// scores, Q_T=8: z[bq][k] partial pass. grid 256 = (b(4), kq4(4), q8(16)),
// 512 thr = kp(64: 2k each, k-quarter=128k) x hs(8: 128h each).
// Per 4h-group: 4 uint loads + 8 GRPPK (8q x 2k) -> EbT sweep = 64 MB total
// (vs 256 MB at Q_T=2): T = M(14.5) + O(27)/8 ~ 18 us predicted.
__global__ __launch_bounds__(512, 4) void scores_z(
    const unsigned short* __restrict__ EbT, const float* __restrict__ Ea,
    const float* __restrict__ v, float* __restrict__ zout)
{
    __shared__ float4 s_eaA[1024];      // Ea q0..3, 16 KB
    __shared__ float4 s_eaB[1024];      // Ea q4..7, 16 KB
    __shared__ float  s_v[1024];        // 4 KB
    __shared__ float  s_part[8][8][128];// [hs][q][k-in-quarter], 32 KB
    const int t = threadIdx.x, bx = blockIdx.x;
    const int b = bx & 3, kq4 = (bx >> 2) & 3, q8 = bx >> 4;
    const int bq0 = b * 128 + q8 * 8;
    const int kp = t & 63;              // k-pair within quarter: k_local = 2kp
    const int hs = t >> 6;              // 8 h-slices of 128

    for (int h = t; h < 1024; h += 512) {
        s_eaA[h] = make_float4(Ea[(size_t)(bq0 + 0) * 1024 + h],
                               Ea[(size_t)(bq0 + 1) * 1024 + h],
                               Ea[(size_t)(bq0 + 2) * 1024 + h],
                               Ea[(size_t)(bq0 + 3) * 1024 + h]);
        s_eaB[h] = make_float4(Ea[(size_t)(bq0 + 4) * 1024 + h],
                               Ea[(size_t)(bq0 + 5) * 1024 + h],
                               Ea[(size_t)(bq0 + 6) * 1024 + h],
                               Ea[(size_t)(bq0 + 7) * 1024 + h]);
        s_v[h] = v[h];
    }
    __syncthreads();

    const int h0 = hs * 128;
    const unsigned* up = (const unsigned*)(EbT + ((size_t)(b * 1024 + h0)) * 512)
                         + kq4 * 64 + kp;
    f32x2 a0 = {0.f,0.f}, a1 = {0.f,0.f}, a2 = {0.f,0.f}, a3 = {0.f,0.f};
    f32x2 a4 = {0.f,0.f}, a5 = {0.f,0.f}, a6 = {0.f,0.f}, a7 = {0.f,0.f};
    const f32x2 one2 = {1.f, 1.f};

    #pragma unroll 2
    for (int hg = 0; hg < 32; ++hg) {   // 4-h groups (128 h per slice)
        const int hb = hg * 4;
        const unsigned r0 = up[(size_t)(hb + 0) * 256];  // h-stride = 256 uints
        const unsigned r1 = up[(size_t)(hb + 1) * 256];
        const unsigned r2 = up[(size_t)(hb + 2) * 256];
        const unsigned r3 = up[(size_t)(hb + 3) * 256];
        #define UNPK(r) f32x2{__builtin_bit_cast(float, (r) << 16),            \
                              __builtin_bit_cast(float, (r) & 0xFFFF0000u)}
        const f32x2 eb0 = UNPK(r0), eb1 = UNPK(r1);
        const f32x2 eb2 = UNPK(r2), eb3 = UNPK(r3);
        #undef UNPK
        const float4 eA0 = s_eaA[h0 + hb + 0], eA1 = s_eaA[h0 + hb + 1];
        const float4 eA2 = s_eaA[h0 + hb + 2], eA3 = s_eaA[h0 + hb + 3];
        const float4 eB0 = s_eaB[h0 + hb + 0], eB1 = s_eaB[h0 + hb + 1];
        const float4 eB2 = s_eaB[h0 + hb + 2], eB3 = s_eaB[h0 + hb + 3];
        const float vw0 = s_v[h0 + hb + 0], vw1 = s_v[h0 + hb + 1];
        const float vw2 = s_v[h0 + hb + 2], vw3 = s_v[h0 + hb + 3];
        const f32x2 vv0 = {vw0, vw0}, vv1 = {vw1, vw1};
        const f32x2 vv2 = {vw2, vw2}, vv3 = {vw3, vw3};

        #define GRPPK(accv, E0, E1, E2, E3) do {                                \
            const f32x2 u0 = eb0 * f32x2{E0, E0} + one2;                        \
            const f32x2 u1 = eb1 * f32x2{E1, E1} + one2;                        \
            const f32x2 u2 = eb2 * f32x2{E2, E2} + one2;                        \
            const f32x2 u3 = eb3 * f32x2{E3, E3} + one2;                        \
            const f32x2 d01 = u0 * u1, d23 = u2 * u3;                           \
            f32x2 n01 = vv0 * u1; n01 = vv1 * u0 + n01;                         \
            f32x2 n23 = vv2 * u3; n23 = vv3 * u2 + n23;                         \
            f32x2 n = n01 * d23; n = n23 * d01 + n;                             \
            const f32x2 den = d01 * d23;                                        \
            const f32x2 r = {__builtin_amdgcn_rcpf(den.x),                      \
                             __builtin_amdgcn_rcpf(den.y)};                     \
            accv = n * r + accv;                                                \
        } while (0)

        GRPPK(a0, eA0.x, eA1.x, eA2.x, eA3.x);
        GRPPK(a1, eA0.y, eA1.y, eA2.y, eA3.y);
        GRPPK(a2, eA0.z, eA1.z, eA2.z, eA3.z);
        GRPPK(a3, eA0.w, eA1.w, eA2.w, eA3.w);
        GRPPK(a4, eB0.x, eB1.x, eB2.x, eB3.x);
        GRPPK(a5, eB0.y, eB1.y, eB2.y, eB3.y);
        GRPPK(a6, eB0.z, eB1.z, eB2.z, eB3.z);
        GRPPK(a7, eB0.w, eB1.w, eB2.w, eB3.w);
        #undef GRPPK
    }
    *(f32x2*)&s_part[hs][0][kp * 2] = a0;
    *(f32x2*)&s_part[hs][1][kp * 2] = a1;
    *(f32x2*)&s_part[hs][2][kp * 2] = a2;
    *(f32x2*)&s_part[hs][3][kp * 2] = a3;
    *(f32x2*)&s_part[hs][4][kp * 2] = a4;
    *(f32x2*)&s_part[hs][5][kp * 2] = a5;
    *(f32x2*)&s_part[hs][6][kp * 2] = a6;
    *(f32x2*)&s_part[hs][7][kp * 2] = a7;
    __syncthreads();

    #pragma unroll
    for (int rep = 0; rep < 2; ++rep) {
        const int idx = rep * 512 + t;
        const int qq = idx >> 7, kk = idx & 127;
        float z = 0.f;
        #pragma unroll
        for (int j = 0; j < 8; ++j) z += s_part[j][qq][kk];
        zout[(size_t)(bq0 + qq) * 512 + kq4 * 128 + kk] = -2.0f * z;
    }
}

// ---------------------------------------------------------------------------
// softmax over k: one block per (b,q); writes attn f32 (output) + bf16 (for PV)
__global__ __launch_bounds__(512) void softmax_kernel(
    const float* __restrict__ zin, float* __restrict__ attn_out,
    short* __restrict__ attnb)
{
    __shared__ float s_red[16];
    const int t = threadIdx.x, bqi = blockIdx.x;
    const float z = zin[(size_t)bqi * 512 + t];
    const int lane = t & 63, wid = t >> 6;

    float m = z;
    #pragma unroll
    for (int off = 32; off > 0; off >>= 1)
        m = fmaxf(m, __shfl_xor(m, off, 64));
    if (lane == 0) s_red[wid] = m;
    __syncthreads();
    float mx = s_red[0];
    #pragma unroll
    for (int w = 1; w < 8; ++w) mx = fmaxf(mx, s_red[w]);
    const float p = __expf(z - mx);
    __syncthreads();   // WAR on s_red

    float sl = p;
    #pragma unroll
    for (int off = 32; off > 0; off >>= 1)
        sl += __shfl_xor(sl, off, 64);
    if (lane == 0) s_red[wid] = sl;
    __syncthreads();
    float s = 0.f;
    #pragma unroll
    for (int w = 0; w < 8; ++w) s += s_red[w];

    const float a = p * (1.0f / s);
    attn_out[(size_t)bqi * 512 + t] = a;
    attnb[(size_t)bqi * 512 + t] = (short)f2bf(a);
}

// ---------------------------------------------------------------------------
// PV GEMM: outh[b][128][1024] = attnb[b][128][512] @ valT[b][1024][512]^T
// 128m x 64n tile, K=512 (8 steps); grid b*16+nt = 64 blocks
__global__ __launch_bounds__(256) void pv_gemm(
    const short* __restrict__ attnb, const short* __restrict__ valT,
    float* __restrict__ outh)
{
    __shared__ short ldsA[2][128][64];
    __shared__ short ldsB[2][64][64];
    const int t = threadIdx.x, bx = blockIdx.x;
    const int b = bx >> 4, nt = bx & 15;
    const int n0 = nt * 64;
    const short* A = attnb + (size_t)b * 128 * 512;                    // [128][512]
    const short* B = valT + (size_t)b * 1024 * 512 + (size_t)n0 * 512; // [64][512] tile

    f32x4 acc[4][2];
    #pragma unroll
    for (int i = 0; i < 4; ++i)
        #pragma unroll
        for (int j = 0; j < 2; ++j) acc[i][j] = f32x4{0.f, 0.f, 0.f, 0.f};

    const int lane = t & 63, wid = t >> 6;
    const int wr = wid >> 1, wc = wid & 1;
    const int fr = lane & 15, fko = (lane >> 4) * 16;

    #define STAGE_PV(buf, k0) do {                                              \
        _Pragma("unroll")                                                       \
        for (int it = 0; it < 4; ++it) {                                        \
            const int idx = it * 256 + t;                                       \
            const int row = idx >> 3, c16 = idx & 7;                            \
            const int sc = c16 ^ (row & 7);                                     \
            GLD16(A + (size_t)row * 512 + (k0) + sc * 8,                        \
                  &ldsA[buf][0][0] + idx * 8);                                  \
        }                                                                       \
        _Pragma("unroll")                                                       \
        for (int it = 0; it < 2; ++it) {                                        \
            const int idx = it * 256 + t;                                       \
            const int row = idx >> 3, c16 = idx & 7;                            \
            const int sc = c16 ^ (row & 7);                                     \
            GLD16(B + (size_t)row * 512 + (k0) + sc * 8,                        \
                  &ldsB[buf][0][0] + idx * 8);                                  \
        }                                                                       \
    } while (0)

    #define COMPUTE_PV(buf) do {                                                \
        _Pragma("unroll")                                                       \
        for (int kk = 0; kk < 2; ++kk) {                                        \
            s16x8 af[4], bfv[2];                                                \
            _Pragma("unroll")                                                   \
            for (int i = 0; i < 4; ++i) {                                       \
                const int rowA = wr * 64 + i * 16 + fr;                         \
                int offA = rowA * 128 + kk * 64 + fko; offA ^= (rowA & 7) << 4; \
                af[i] = *(const s16x8*)((const char*)&ldsA[buf][0][0] + offA);  \
            }                                                                   \
            _Pragma("unroll")                                                   \
            for (int ni = 0; ni < 2; ++ni) {                                    \
                const int rowB = wc * 32 + ni * 16 + fr;                        \
                int offB = rowB * 128 + kk * 64 + fko; offB ^= (rowB & 7) << 4; \
                bfv[ni] = *(const s16x8*)((const char*)&ldsB[buf][0][0] + offB);\
            }                                                                   \
            _Pragma("unroll")                                                   \
            for (int mi = 0; mi < 4; ++mi)                                      \
                _Pragma("unroll")                                               \
                for (int ni = 0; ni < 2; ++ni)                                  \
                    acc[mi][ni] = __builtin_amdgcn_mfma_f32_16x16x32_bf16(      \
                                      af[mi], bfv[ni], acc[mi][ni], 0, 0, 0);   \
        }                                                                       \
    } while (0)

    STAGE_PV(0, 0);
    __syncthreads();
    int cur = 0;
    for (int s = 0; s < 7; ++s) {
        STAGE_PV(cur ^ 1, (s + 1) * 64);
        COMPUTE_PV(cur);
        __syncthreads();
        cur ^= 1;
    }
    COMPUTE_PV(cur);

    const int row0 = (lane >> 4) * 4;
    #pragma unroll
    for (int ni = 0; ni < 2; ++ni) {
        const int n = n0 + wc * 32 + ni * 16 + fr;
        #pragma unroll
        for (int mi = 0; mi < 4; ++mi) {
            const int m = wr * 64 + mi * 16 + row0;
            #pragma unroll
            for (int j = 0; j < 4; ++j)
                outh[(size_t)(b * 128 + m + j) * 1024 + n] = acc[mi][ni][j];
        }
    }
    #undef STAGE_PV
    #undef COMPUTE_PV
}

extern "C" void kernel_launch(void* const* d_in, const int* in_sizes, int n_in,
                              void* d_out, int out_size, void* d_ws, size_t ws_size,
                              hipStream_t stream)
{
    const float* query = (const float*)d_in[0];
    const float* key   = (const float*)d_in[1];
    const float* value = (const float*)d_in[2];
    const float* Wq    = (const float*)d_in[3];
    const float* bq    = (const float*)d_in[4];
    const float* Wk    = (const float*)d_in[5];
    const float* v     = (const float*)d_in[6];
    float* out = (float*)d_out;

    // workspace layout (21 MB):
    char* w = (char*)d_ws;
    float*          ws_Ea  = (float*)w;                       // 2 MB
    unsigned short* ws_EbT = (unsigned short*)(w + (2u << 20)); // 4 MB (bf16)
    short* Qb     = (short*)(w + (6u << 20));                 // 1 MB
    short* Kb     = (short*)(w + (7u << 20));                 // 4 MB
    short* WqT    = (short*)(w + (11u << 20));                // 2 MB
    short* WkT    = (short*)(w + (13u << 20));                // 2 MB
    short* valT   = (short*)(w + (15u << 20));                // 4 MB
    short* attnb  = (short*)(w + (19u << 20));                // 0.5 MB
    float* zbuf   = (float*)(w + (20u << 20));                // 1 MB

    float* out_h    = out;                                // [512][1024]
    float* out_attn = out + (size_t)NB * NTQ * NH;        // [512][512]

    prep_kernel   <<<dim3(1664), dim3(256), 0, stream>>>(query, key, Wq, Wk, value,
                                                         Qb, Kb, WqT, WkT, valT);
    mm_kernel     <<<dim3(320),  dim3(256), 0, stream>>>(Qb, Kb, WqT, WkT, bq, ws_Ea, ws_EbT);
    scores_z      <<<dim3(256),  dim3(512), 0, stream>>>(ws_EbT, ws_Ea, v, zbuf);
    softmax_kernel<<<dim3(512),  dim3(512), 0, stream>>>(zbuf, out_attn, attnb);
    pv_gemm       <<<dim3(64),   dim3(256), 0, stream>>>(attnb, valT, out_h);
}

// Round 23
// 65.960 us; speedup vs baseline: 1.0343x; 1.0343x over previous
//
#include <hip/hip_runtime.h>
#include <hip/hip_bf16.h>

typedef float f32x4 __attribute__((ext_vector_type(4)));
typedef float f32x2 __attribute__((ext_vector_type(2)));
typedef short s16x8 __attribute__((ext_vector_type(8)));
typedef short s16x4 __attribute__((ext_vector_type(4)));

#define NB  4
#define NTQ 128
#define NTK 512
#define NH  1024
#define ECLAMP 3.0e4f   // keeps 4-way u-products < f32 max; tanh delta < 1e-9

__device__ __forceinline__ unsigned short f2bf(float x) {
    unsigned u = __builtin_bit_cast(unsigned, x);
    u += 0x7FFFu + ((u >> 16) & 1u);          // round-to-nearest-even
    return (unsigned short)(u >> 16);
}

#define K2E  2.8853900817779268f   // 2*log2(e): exp2(K2E*x) = e^{2x}

// async global->LDS 16B: linear LDS dest (wave base + lane*16), per-lane global src
#define GLD16(gp, lp) __builtin_amdgcn_global_load_lds( \
    (const __attribute__((address_space(1))) unsigned int*)(gp), \
    (__attribute__((address_space(3))) unsigned int*)(lp), 16, 0, 0)

// ---------------------------------------------------------------------------
// prep: blocks [0,640): bf16 copy Q|K (float4 coalesced).
// blocks [640,1664): 64x64 transpose-convert tiles: Wq->WqT, Wk->WkT, value->valT.
__global__ __launch_bounds__(256) void prep_kernel(
    const float* __restrict__ Q, const float* __restrict__ K,
    const float* __restrict__ Wq, const float* __restrict__ Wk,
    const float* __restrict__ value,
    short* __restrict__ Qb, short* __restrict__ Kb,
    short* __restrict__ WqT, short* __restrict__ WkT, short* __restrict__ valT)
{
    const int t = threadIdx.x, bx = blockIdx.x;
    if (bx < 640) {   // copy region: blocks [0,128) = Q, [128,640) = K
        const float* src; short* dst; size_t base;
        if (bx < 128) { src = Q; dst = Qb; base = (size_t)bx * 4096; }
        else          { src = K; dst = Kb; base = (size_t)(bx - 128) * 4096; }
        #pragma unroll
        for (int i = 0; i < 4; ++i) {
            const size_t off = base + (size_t)(i * 256 + t) * 4;
            const float4 vv = *(const float4*)(src + off);
            s16x4 o = { (short)f2bf(vv.x), (short)f2bf(vv.y),
                        (short)f2bf(vv.z), (short)f2bf(vv.w) };
            *(s16x4*)(dst + off) = o;
        }
        return;
    }
    // transpose region
    __shared__ float tile[64][65];
    const int i = bx - 640;
    const float* src; short* dst; int Cs, Rs, r0, c0;
    if (i < 256)      { src = Wq; dst = WqT; Cs = 1024; Rs = 1024; r0 = (i >> 4) * 64; c0 = (i & 15) * 64; }
    else if (i < 512) { const int j = i - 256; src = Wk; dst = WkT; Cs = 1024; Rs = 1024; r0 = (j >> 4) * 64; c0 = (j & 15) * 64; }
    else {
        const int j = i - 512, b = j >> 7, ti = j & 127;
        src = value + (size_t)b * 512 * 1024; dst = valT + (size_t)b * 1024 * 512;
        Cs = 1024; Rs = 512; r0 = (ti >> 4) * 64; c0 = (ti & 15) * 64;
    }
    {   // load 64x64 f32 tile, coalesced 256B/row
        const int c = (t & 15) * 4;
        #pragma unroll
        for (int it = 0; it < 4; ++it) {
            const int r = (t >> 4) + it * 16;
            const float4 vv = *(const float4*)(src + (size_t)(r0 + r) * Cs + c0 + c);
            tile[r][c + 0] = vv.x; tile[r][c + 1] = vv.y;
            tile[r][c + 2] = vv.z; tile[r][c + 3] = vv.w;
        }
    }
    __syncthreads();
    {   // write transposed: 128B per 16-lane group
        const int r = (t & 15) * 4;
        #pragma unroll
        for (int it = 0; it < 4; ++it) {
            const int c = (t >> 4) + it * 16;
            s16x4 o = { (short)f2bf(tile[r + 0][c]), (short)f2bf(tile[r + 1][c]),
                        (short)f2bf(tile[r + 2][c]), (short)f2bf(tile[r + 3][c]) };
            *(s16x4*)(dst + (size_t)(c0 + c) * Rs + r0 + r) = o;
        }
    }
}

// ---------------------------------------------------------------------------
// main GEMMs with epilogue exp (clamped at ECLAMP): 64x64 tiles for occupancy
// (640 blocks = 2.5 blocks/CU vs 1.25 at 128x64).
// swz blocks [0,128): Ea f32; [128,640): EbT[b][h][k] transposed, bf16.
// BK=64, dbuf LDS via global_load_lds, XOR-swizzled (rule #21).
__global__ __launch_bounds__(256) void mm_kernel(
    const short* __restrict__ Qb, const short* __restrict__ Kb,
    const short* __restrict__ WqT, const short* __restrict__ WkT,
    const float* __restrict__ bq,
    float* __restrict__ Ea_out, unsigned short* __restrict__ EbT)
{
    __shared__ short ldsA[2][64][64];    // 16 KB
    __shared__ short ldsB[2][64][64];    // 16 KB
    const int t = threadIdx.x;
    const int bx0 = blockIdx.x;
    const int bx = (bx0 & 7) * 80 + (bx0 >> 3);   // XCD-chunked swizzle (640%8==0)
    const bool g1 = bx < 128;
    const short *A, *B; int m0, n0;
    if (g1) { A = Qb; B = WqT; m0 = (bx >> 4) * 64; n0 = (bx & 15) * 64; }
    else    { const int i = bx - 128; A = Kb; B = WkT; m0 = (i >> 4) * 64; n0 = (i & 15) * 64; }
    A += (size_t)m0 * 1024; B += (size_t)n0 * 1024;

    f32x4 acc[2][2];
    #pragma unroll
    for (int i = 0; i < 2; ++i)
        #pragma unroll
        for (int j = 0; j < 2; ++j) acc[i][j] = f32x4{0.f, 0.f, 0.f, 0.f};

    const int lane = t & 63, wid = t >> 6;
    const int wr = wid >> 1, wc = wid & 1;          // waves 2x2 over (32m,32n)
    const int fr = lane & 15, fko = (lane >> 4) * 16;   // byte offset in 128B row

    #define STAGE_MM(buf, k0) do {                                              \
        _Pragma("unroll")                                                       \
        for (int it = 0; it < 2; ++it) {                                        \
            const int idx = it * 256 + t;                                       \
            const int row = idx >> 3, c16 = idx & 7;                            \
            const int sc = c16 ^ (row & 7);                                     \
            GLD16(A + (size_t)row * 1024 + (k0) + sc * 8,                       \
                  &ldsA[buf][0][0] + idx * 8);                                  \
        }                                                                       \
        _Pragma("unroll")                                                       \
        for (int it = 0; it < 2; ++it) {                                        \
            const int idx = it * 256 + t;                                       \
            const int row = idx >> 3, c16 = idx & 7;                            \
            const int sc = c16 ^ (row & 7);                                     \
            GLD16(B + (size_t)row * 1024 + (k0) + sc * 8,                       \
                  &ldsB[buf][0][0] + idx * 8);                                  \
        }                                                                       \
    } while (0)

    #define COMPUTE_MM(buf) do {                                                \
        _Pragma("unroll")                                                       \
        for (int kk = 0; kk < 2; ++kk) {                                        \
            s16x8 af[2], bfv[2];                                                \
            _Pragma("unroll")                                                   \
            for (int i = 0; i < 2; ++i) {                                       \
                const int rowA = wr * 32 + i * 16 + fr;                         \
                int offA = rowA * 128 + kk * 64 + fko; offA ^= (rowA & 7) << 4; \
                af[i] = *(const s16x8*)((const char*)&ldsA[buf][0][0] + offA);  \
                const int rowB = wc * 32 + i * 16 + fr;                         \
                int offB = rowB * 128 + kk * 64 + fko; offB ^= (rowB & 7) << 4; \
                bfv[i] = *(const s16x8*)((const char*)&ldsB[buf][0][0] + offB); \
            }                                                                   \
            _Pragma("unroll")                                                   \
            for (int mi = 0; mi < 2; ++mi)                                      \
                _Pragma("unroll")                                               \
                for (int ni = 0; ni < 2; ++ni)                                  \
                    acc[mi][ni] = __builtin_amdgcn_mfma_f32_16x16x32_bf16(      \
                                      af[mi], bfv[ni], acc[mi][ni], 0, 0, 0);   \
        }                                                                       \
    } while (0)

    STAGE_MM(0, 0);
    __syncthreads();
    int cur = 0;
    for (int s = 0; s < 15; ++s) {
        STAGE_MM(cur ^ 1, (s + 1) * 64);
        COMPUTE_MM(cur);
        __syncthreads();
        cur ^= 1;
    }
    COMPUTE_MM(cur);

    // D layout: col = lane&15, row = (lane>>4)*4 + reg
    const int row0 = (lane >> 4) * 4;
    if (g1) {
        #pragma unroll
        for (int ni = 0; ni < 2; ++ni) {
            const int n = n0 + wc * 32 + ni * 16 + fr;
            const float bias = bq[n];
            #pragma unroll
            for (int mi = 0; mi < 2; ++mi) {
                const int m = m0 + wr * 32 + mi * 16 + row0;
                #pragma unroll
                for (int j = 0; j < 4; ++j)
                    Ea_out[(size_t)(m + j) * 1024 + n] =
                        fminf(__builtin_amdgcn_exp2f(K2E * (acc[mi][ni][j] + bias)), ECLAMP);
            }
        }
    } else {
        #pragma unroll
        for (int mi = 0; mi < 2; ++mi) {
            const int m = m0 + wr * 32 + mi * 16 + row0;
            const int b = m >> 9, kk = m & 511;
            #pragma unroll
            for (int ni = 0; ni < 2; ++ni) {
                const int n = n0 + wc * 32 + ni * 16 + fr;
                s16x4 ev;
                #pragma unroll
                for (int j = 0; j < 4; ++j)
                    ev[j] = (short)f2bf(fminf(__builtin_amdgcn_exp2f(K2E * acc[mi][ni][j]), ECLAMP));
                *(s16x4*)&EbT[((size_t)b * 1024 + n) * 512 + kk] = ev;
            }
        }
    }
    #undef STAGE_MM
    #undef COMPUTE_MM
}

// ---------------------------------------------------------------------------
// fused scores+softmax (R16-proven config, best measured): block = (b, q-pair),
// 256 blocks x 1024 thr = kq(128) x hs(8). Packed f32x2, 4-way h-combine.
__global__ __launch_bounds__(1024, 4) void scores_softmax(
    const unsigned short* __restrict__ EbT, const float* __restrict__ Ea,
    const float* __restrict__ v,
    float* __restrict__ attn_out, short* __restrict__ attnb)
{
    __shared__ float4 s_eav[1024];       // {Ea_q0[h], Ea_q1[h], v[h], -} 16 KB
    __shared__ float  s_part[8][2][512]; // [hs][q][k] partials, 32 KB
    __shared__ float  s_red[16];
    const int t = threadIdx.x, bx = blockIdx.x;
    const int b = bx & 3;                // batch pinned per XCD pair
    const int q2 = bx >> 2;              // 0..63
    const int bq0 = b * 128 + q2 * 2;
    const int kq = t & 127;              // k-quad: k = 4kq..4kq+3 (full 512)
    const int hs = t >> 7;               // 8 h-slices of 128
    const int lane = t & 63, wid = t >> 6;

    s_eav[t] = make_float4(Ea[(size_t)(bq0 + 0) * 1024 + t],
                           Ea[(size_t)(bq0 + 1) * 1024 + t],
                           v[t], 0.f);
    __syncthreads();

    const int h0 = hs * 128;
    const uint2* up = (const uint2*)(EbT + ((size_t)(b * 1024 + h0)) * 512) + kq;
    f32x2 a0lo = {0.f, 0.f}, a0hi = {0.f, 0.f};   // q0: {k0,k1}, {k2,k3}
    f32x2 a1lo = {0.f, 0.f}, a1hi = {0.f, 0.f};   // q1
    const f32x2 one2 = {1.f, 1.f};

    #pragma unroll 2
    for (int hg = 0; hg < 32; ++hg) {    // 4-h groups (128 h per slice)
        const int hb = hg * 4;
        const uint2 r0 = up[(size_t)(hb + 0) * 128];   // h-stride = 128 uint2
        const uint2 r1 = up[(size_t)(hb + 1) * 128];
        const uint2 r2 = up[(size_t)(hb + 2) * 128];
        const uint2 r3 = up[(size_t)(hb + 3) * 128];
        const float4 ev0 = s_eav[h0 + hb + 0];
        const float4 ev1 = s_eav[h0 + hb + 1];
        const float4 ev2 = s_eav[h0 + hb + 2];
        const float4 ev3 = s_eav[h0 + hb + 3];
        #define UNPK(r) f32x2{__builtin_bit_cast(float, (r) << 16),            \
                              __builtin_bit_cast(float, (r) & 0xFFFF0000u)}
        const f32x2 b0lo = UNPK(r0.x), b0hi = UNPK(r0.y);
        const f32x2 b1lo = UNPK(r1.x), b1hi = UNPK(r1.y);
        const f32x2 b2lo = UNPK(r2.x), b2hi = UNPK(r2.y);
        const f32x2 b3lo = UNPK(r3.x), b3hi = UNPK(r3.y);
        #undef UNPK
        const f32x2 vv0 = {ev0.z, ev0.z}, vv1 = {ev1.z, ev1.z};
        const f32x2 vv2 = {ev2.z, ev2.z}, vv3 = {ev3.z, ev3.z};

        #define GRPPK(accv, EA0, EA1, EA2, EA3, B0, B1, B2, B3) do {            \
            const f32x2 u0 = B0 * EA0 + one2;                                   \
            const f32x2 u1 = B1 * EA1 + one2;                                   \
            const f32x2 u2 = B2 * EA2 + one2;                                   \
            const f32x2 u3 = B3 * EA3 + one2;                                   \
            const f32x2 d01 = u0 * u1, d23 = u2 * u3;                           \
            f32x2 n01 = vv0 * u1; n01 = vv1 * u0 + n01;                         \
            f32x2 n23 = vv2 * u3; n23 = vv3 * u2 + n23;                         \
            f32x2 n = n01 * d23; n = n23 * d01 + n;                             \
            const f32x2 den = d01 * d23;                                        \
            const f32x2 r = {__builtin_amdgcn_rcpf(den.x),                      \
                             __builtin_amdgcn_rcpf(den.y)};                     \
            accv = n * r + accv;                                                \
        } while (0)

        {   // q0
            const f32x2 e0 = {ev0.x, ev0.x}, e1 = {ev1.x, ev1.x};
            const f32x2 e2 = {ev2.x, ev2.x}, e3 = {ev3.x, ev3.x};
            GRPPK(a0lo, e0, e1, e2, e3, b0lo, b1lo, b2lo, b3lo);
            GRPPK(a0hi, e0, e1, e2, e3, b0hi, b1hi, b2hi, b3hi);
        }
        {   // q1
            const f32x2 e0 = {ev0.y, ev0.y}, e1 = {ev1.y, ev1.y};
            const f32x2 e2 = {ev2.y, ev2.y}, e3 = {ev3.y, ev3.y};
            GRPPK(a1lo, e0, e1, e2, e3, b0lo, b1lo, b2lo, b3lo);
            GRPPK(a1hi, e0, e1, e2, e3, b0hi, b1hi, b2hi, b3hi);
        }
        #undef GRPPK
    }
    *(f32x4*)&s_part[hs][0][kq * 4] = f32x4{a0lo.x, a0lo.y, a0hi.x, a0hi.y};
    *(f32x4*)&s_part[hs][1][kq * 4] = f32x4{a1lo.x, a1lo.y, a1hi.x, a1hi.y};
    __syncthreads();

    // combine + softmax: thread t -> (qq = t>>9, kk = t&511)
    const int kk = t & 511, qq = t >> 9;
    float z = 0.f;
    #pragma unroll
    for (int j = 0; j < 8; ++j) z += s_part[j][qq][kk];
    z *= -2.0f;

    // per-q max (waves 0-7 = q0, waves 8-15 = q1)
    float m = z;
    #pragma unroll
    for (int off = 32; off > 0; off >>= 1)
        m = fmaxf(m, __shfl_xor(m, off, 64));
    if (lane == 0) s_red[wid] = m;
    __syncthreads();
    float mx = s_red[qq * 8];
    #pragma unroll
    for (int w = 1; w < 8; ++w) mx = fmaxf(mx, s_red[qq * 8 + w]);
    const float p = __expf(z - mx);
    __syncthreads();   // WAR on s_red

    // per-q sum
    float sl = p;
    #pragma unroll
    for (int off = 32; off > 0; off >>= 1)
        sl += __shfl_xor(sl, off, 64);
    if (lane == 0) s_red[wid] = sl;
    __syncthreads();
    float s = 0.f;
    #pragma unroll
    for (int w = 0; w < 8; ++w) s += s_red[qq * 8 + w];

    const float a = p * (1.0f / s);
    attn_out[(size_t)(bq0 + qq) * 512 + kk] = a;
    attnb[(size_t)(bq0 + qq) * 512 + kk] = (short)f2bf(a);
}

// ---------------------------------------------------------------------------
// PV GEMM: outh[b][128][1024] = attnb[b][128][512] @ valT[b][1024][512]^T
// 128m x 64n tile, K=512 (8 steps); grid b*16+nt = 64 blocks
__global__ __launch_bounds__(256) void pv_gemm(
    const short* __restrict__ attnb, const short* __restrict__ valT,
    float* __restrict__ outh)
{
    __shared__ short ldsA[2][128][64];
    __shared__ short ldsB[2][64][64];
    const int t = threadIdx.x, bx = blockIdx.x;
    const int b = bx >> 4, nt = bx & 15;
    const int n0 = nt * 64;
    const short* A = attnb + (size_t)b * 128 * 512;                    // [128][512]
    const short* B = valT + (size_t)b * 1024 * 512 + (size_t)n0 * 512; // [64][512] tile

    f32x4 acc[4][2];
    #pragma unroll
    for (int i = 0; i < 4; ++i)
        #pragma unroll
        for (int j = 0; j < 2; ++j) acc[i][j] = f32x4{0.f, 0.f, 0.f, 0.f};

    const int lane = t & 63, wid = t >> 6;
    const int wr = wid >> 1, wc = wid & 1;
    const int fr = lane & 15, fko = (lane >> 4) * 16;

    #define STAGE_PV(buf, k0) do {                                              \
        _Pragma("unroll")                                                       \
        for (int it = 0; it < 4; ++it) {                                        \
            const int idx = it * 256 + t;                                       \
            const int row = idx >> 3, c16 = idx & 7;                            \
            const int sc = c16 ^ (row & 7);                                     \
            GLD16(A + (size_t)row * 512 + (k0) + sc * 8,                        \
                  &ldsA[buf][0][0] + idx * 8);                                  \
        }                                                                       \
        _Pragma("unroll")                                                       \
        for (int it = 0; it < 2; ++it) {                                        \
            const int idx = it * 256 + t;                                       \
            const int row = idx >> 3, c16 = idx & 7;                            \
            const int sc = c16 ^ (row & 7);                                     \
            GLD16(B + (size_t)row * 512 + (k0) + sc * 8,                        \
                  &ldsB[buf][0][0] + idx * 8);                                  \
        }                                                                       \
    } while (0)

    #define COMPUTE_PV(buf) do {                                                \
        _Pragma("unroll")                                                       \
        for (int kk = 0; kk < 2; ++kk) {                                        \
            s16x8 af[4], bfv[2];                                                \
            _Pragma("unroll")                                                   \
            for (int i = 0; i < 4; ++i) {                                       \
                const int rowA = wr * 64 + i * 16 + fr;                         \
                int offA = rowA * 128 + kk * 64 + fko; offA ^= (rowA & 7) << 4; \
                af[i] = *(const s16x8*)((const char*)&ldsA[buf][0][0] + offA);  \
            }                                                                   \
            _Pragma("unroll")                                                   \
            for (int ni = 0; ni < 2; ++ni) {                                    \
                const int rowB = wc * 32 + ni * 16 + fr;                        \
                int offB = rowB * 128 + kk * 64 + fko; offB ^= (rowB & 7) << 4; \
                bfv[ni] = *(const s16x8*)((const char*)&ldsB[buf][0][0] + offB);\
            }                                                                   \
            _Pragma("unroll")                                                   \
            for (int mi = 0; mi < 4; ++mi)                                      \
                _Pragma("unroll")                                               \
                for (int ni = 0; ni < 2; ++ni)                                  \
                    acc[mi][ni] = __builtin_amdgcn_mfma_f32_16x16x32_bf16(      \
                                      af[mi], bfv[ni], acc[mi][ni], 0, 0, 0);   \
        }                                                                       \
    } while (0)

    STAGE_PV(0, 0);
    __syncthreads();
    int cur = 0;
    for (int s = 0; s < 7; ++s) {
        STAGE_PV(cur ^ 1, (s + 1) * 64);
        COMPUTE_PV(cur);
        __syncthreads();
        cur ^= 1;
    }
    COMPUTE_PV(cur);

    const int row0 = (lane >> 4) * 4;
    #pragma unroll
    for (int ni = 0; ni < 2; ++ni) {
        const int n = n0 + wc * 32 + ni * 16 + fr;
        #pragma unroll
        for (int mi = 0; mi < 4; ++mi) {
            const int m = wr * 64 + mi * 16 + row0;
            #pragma unroll
            for (int j = 0; j < 4; ++j)
                outh[(size_t)(b * 128 + m + j) * 1024 + n] = acc[mi][ni][j];
        }
    }
    #undef STAGE_PV
    #undef COMPUTE_PV
}

extern "C" void kernel_launch(void* const* d_in, const int* in_sizes, int n_in,
                              void* d_out, int out_size, void* d_ws, size_t ws_size,
                              hipStream_t stream)
{
    const float* query = (const float*)d_in[0];
    const float* key   = (const float*)d_in[1];
    const float* value = (const float*)d_in[2];
    const float* Wq    = (const float*)d_in[3];
    const float* bq    = (const float*)d_in[4];
    const float* Wk    = (const float*)d_in[5];
    const float* v     = (const float*)d_in[6];
    float* out = (float*)d_out;

    // workspace layout (20 MB):
    char* w = (char*)d_ws;
    float*          ws_Ea  = (float*)w;                       // 2 MB
    unsigned short* ws_EbT = (unsigned short*)(w + (2u << 20)); // 4 MB (bf16)
    short* Qb     = (short*)(w + (6u << 20));                 // 1 MB
    short* Kb     = (short*)(w + (7u << 20));                 // 4 MB
    short* WqT    = (short*)(w + (11u << 20));                // 2 MB
    short* WkT    = (short*)(w + (13u << 20));                // 2 MB
    short* valT   = (short*)(w + (15u << 20));                // 4 MB
    short* attnb  = (short*)(w + (19u << 20));                // 0.5 MB

    float* out_h    = out;                                // [512][1024]
    float* out_attn = out + (size_t)NB * NTQ * NH;        // [512][512]

    prep_kernel   <<<dim3(1664), dim3(256),  0, stream>>>(query, key, Wq, Wk, value,
                                                          Qb, Kb, WqT, WkT, valT);
    mm_kernel     <<<dim3(640),  dim3(256),  0, stream>>>(Qb, Kb, WqT, WkT, bq, ws_Ea, ws_EbT);
    scores_softmax<<<dim3(256),  dim3(1024), 0, stream>>>(ws_EbT, ws_Ea, v, out_attn, attnb);
    pv_gemm       <<<dim3(64),   dim3(256),  0, stream>>>(attnb, valT, out_h);
}

// Round 24
// 65.077 us; speedup vs baseline: 1.0484x; 1.0136x over previous
//
#include <hip/hip_runtime.h>
#include <hip/hip_bf16.h>

typedef float f32x4 __attribute__((ext_vector_type(4)));
typedef float f32x2 __attribute__((ext_vector_type(2)));
typedef short s16x8 __attribute__((ext_vector_type(8)));
typedef short s16x4 __attribute__((ext_vector_type(4)));

#define NB  4
#define NTQ 128
#define NTK 512
#define NH  1024
#define ECLAMP 3.0e4f   // keeps 4-way u-products < f32 max; tanh delta < 1e-9

__device__ __forceinline__ unsigned short f2bf(float x) {
    unsigned u = __builtin_bit_cast(unsigned, x);
    u += 0x7FFFu + ((u >> 16) & 1u);          // round-to-nearest-even
    return (unsigned short)(u >> 16);
}

#define K2E  2.8853900817779268f   // 2*log2(e): exp2(K2E*x) = e^{2x}

// async global->LDS 16B: linear LDS dest (wave base + lane*16), per-lane global src
#define GLD16(gp, lp) __builtin_amdgcn_global_load_lds( \
    (const __attribute__((address_space(1))) unsigned int*)(gp), \
    (__attribute__((address_space(3))) unsigned int*)(lp), 16, 0, 0)

// ---------------------------------------------------------------------------
// prep: blocks [0,640): bf16 copy Q|K (float4 coalesced).
// blocks [640,1664): 64x64 transpose-convert tiles: Wq->WqT, Wk->WkT, value->valT.
__global__ __launch_bounds__(256) void prep_kernel(
    const float* __restrict__ Q, const float* __restrict__ K,
    const float* __restrict__ Wq, const float* __restrict__ Wk,
    const float* __restrict__ value,
    short* __restrict__ Qb, short* __restrict__ Kb,
    short* __restrict__ WqT, short* __restrict__ WkT, short* __restrict__ valT)
{
    const int t = threadIdx.x, bx = blockIdx.x;
    if (bx < 640) {   // copy region: blocks [0,128) = Q, [128,640) = K
        const float* src; short* dst; size_t base;
        if (bx < 128) { src = Q; dst = Qb; base = (size_t)bx * 4096; }
        else          { src = K; dst = Kb; base = (size_t)(bx - 128) * 4096; }
        #pragma unroll
        for (int i = 0; i < 4; ++i) {
            const size_t off = base + (size_t)(i * 256 + t) * 4;
            const float4 vv = *(const float4*)(src + off);
            s16x4 o = { (short)f2bf(vv.x), (short)f2bf(vv.y),
                        (short)f2bf(vv.z), (short)f2bf(vv.w) };
            *(s16x4*)(dst + off) = o;
        }
        return;
    }
    // transpose region
    __shared__ float tile[64][65];
    const int i = bx - 640;
    const float* src; short* dst; int Cs, Rs, r0, c0;
    if (i < 256)      { src = Wq; dst = WqT; Cs = 1024; Rs = 1024; r0 = (i >> 4) * 64; c0 = (i & 15) * 64; }
    else if (i < 512) { const int j = i - 256; src = Wk; dst = WkT; Cs = 1024; Rs = 1024; r0 = (j >> 4) * 64; c0 = (j & 15) * 64; }
    else {
        const int j = i - 512, b = j >> 7, ti = j & 127;
        src = value + (size_t)b * 512 * 1024; dst = valT + (size_t)b * 1024 * 512;
        Cs = 1024; Rs = 512; r0 = (ti >> 4) * 64; c0 = (ti & 15) * 64;
    }
    {   // load 64x64 f32 tile, coalesced 256B/row
        const int c = (t & 15) * 4;
        #pragma unroll
        for (int it = 0; it < 4; ++it) {
            const int r = (t >> 4) + it * 16;
            const float4 vv = *(const float4*)(src + (size_t)(r0 + r) * Cs + c0 + c);
            tile[r][c + 0] = vv.x; tile[r][c + 1] = vv.y;
            tile[r][c + 2] = vv.z; tile[r][c + 3] = vv.w;
        }
    }
    __syncthreads();
    {   // write transposed: 128B per 16-lane group
        const int r = (t & 15) * 4;
        #pragma unroll
        for (int it = 0; it < 4; ++it) {
            const int c = (t >> 4) + it * 16;
            s16x4 o = { (short)f2bf(tile[r + 0][c]), (short)f2bf(tile[r + 1][c]),
                        (short)f2bf(tile[r + 2][c]), (short)f2bf(tile[r + 3][c]) };
            *(s16x4*)(dst + (size_t)(c0 + c) * Rs + r0 + r) = o;
        }
    }
}

// ---------------------------------------------------------------------------
// main GEMMs with epilogue exp (clamped at ECLAMP): 64x64 tiles.
// swz blocks [0,128): Ea f32; [128,640): EbT[b][h][k] transposed, bf16.
// BK=64, dbuf LDS via global_load_lds, XOR-swizzled (rule #21).
__global__ __launch_bounds__(256) void mm_kernel(
    const short* __restrict__ Qb, const short* __restrict__ Kb,
    const short* __restrict__ WqT, const short* __restrict__ WkT,
    const float* __restrict__ bq,
    float* __restrict__ Ea_out, unsigned short* __restrict__ EbT)
{
    __shared__ short ldsA[2][64][64];    // 16 KB
    __shared__ short ldsB[2][64][64];    // 16 KB
    const int t = threadIdx.x;
    const int bx0 = blockIdx.x;
    const int bx = (bx0 & 7) * 80 + (bx0 >> 3);   // XCD-chunked swizzle (640%8==0)
    const bool g1 = bx < 128;
    const short *A, *B; int m0, n0;
    if (g1) { A = Qb; B = WqT; m0 = (bx >> 4) * 64; n0 = (bx & 15) * 64; }
    else    { const int i = bx - 128; A = Kb; B = WkT; m0 = (i >> 4) * 64; n0 = (i & 15) * 64; }
    A += (size_t)m0 * 1024; B += (size_t)n0 * 1024;

    f32x4 acc[2][2];
    #pragma unroll
    for (int i = 0; i < 2; ++i)
        #pragma unroll
        for (int j = 0; j < 2; ++j) acc[i][j] = f32x4{0.f, 0.f, 0.f, 0.f};

    const int lane = t & 63, wid = t >> 6;
    const int wr = wid >> 1, wc = wid & 1;          // waves 2x2 over (32m,32n)
    const int fr = lane & 15, fko = (lane >> 4) * 16;   // byte offset in 128B row

    #define STAGE_MM(buf, k0) do {                                              \
        _Pragma("unroll")                                                       \
        for (int it = 0; it < 2; ++it) {                                        \
            const int idx = it * 256 + t;                                       \
            const int row = idx >> 3, c16 = idx & 7;                            \
            const int sc = c16 ^ (row & 7);                                     \
            GLD16(A + (size_t)row * 1024 + (k0) + sc * 8,                       \
                  &ldsA[buf][0][0] + idx * 8);                                  \
        }                                                                       \
        _Pragma("unroll")                                                       \
        for (int it = 0; it < 2; ++it) {                                        \
            const int idx = it * 256 + t;                                       \
            const int row = idx >> 3, c16 = idx & 7;                            \
            const int sc = c16 ^ (row & 7);                                     \
            GLD16(B + (size_t)row * 1024 + (k0) + sc * 8,                       \
                  &ldsB[buf][0][0] + idx * 8);                                  \
        }                                                                       \
    } while (0)

    #define COMPUTE_MM(buf) do {                                                \
        _Pragma("unroll")                                                       \
        for (int kk = 0; kk < 2; ++kk) {                                        \
            s16x8 af[2], bfv[2];                                                \
            _Pragma("unroll")                                                   \
            for (int i = 0; i < 2; ++i) {                                       \
                const int rowA = wr * 32 + i * 16 + fr;                         \
                int offA = rowA * 128 + kk * 64 + fko; offA ^= (rowA & 7) << 4; \
                af[i] = *(const s16x8*)((const char*)&ldsA[buf][0][0] + offA);  \
                const int rowB = wc * 32 + i * 16 + fr;                         \
                int offB = rowB * 128 + kk * 64 + fko; offB ^= (rowB & 7) << 4; \
                bfv[i] = *(const s16x8*)((const char*)&ldsB[buf][0][0] + offB); \
            }                                                                   \
            _Pragma("unroll")                                                   \
            for (int mi = 0; mi < 2; ++mi)                                      \
                _Pragma("unroll")                                               \
                for (int ni = 0; ni < 2; ++ni)                                  \
                    acc[mi][ni] = __builtin_amdgcn_mfma_f32_16x16x32_bf16(      \
                                      af[mi], bfv[ni], acc[mi][ni], 0, 0, 0);   \
        }                                                                       \
    } while (0)

    STAGE_MM(0, 0);
    __syncthreads();
    int cur = 0;
    for (int s = 0; s < 15; ++s) {
        STAGE_MM(cur ^ 1, (s + 1) * 64);
        COMPUTE_MM(cur);
        __syncthreads();
        cur ^= 1;
    }
    COMPUTE_MM(cur);

    // D layout: col = lane&15, row = (lane>>4)*4 + reg
    const int row0 = (lane >> 4) * 4;
    if (g1) {
        #pragma unroll
        for (int ni = 0; ni < 2; ++ni) {
            const int n = n0 + wc * 32 + ni * 16 + fr;
            const float bias = bq[n];
            #pragma unroll
            for (int mi = 0; mi < 2; ++mi) {
                const int m = m0 + wr * 32 + mi * 16 + row0;
                #pragma unroll
                for (int j = 0; j < 4; ++j)
                    Ea_out[(size_t)(m + j) * 1024 + n] =
                        fminf(__builtin_amdgcn_exp2f(K2E * (acc[mi][ni][j] + bias)), ECLAMP);
            }
        }
    } else {
        #pragma unroll
        for (int mi = 0; mi < 2; ++mi) {
            const int m = m0 + wr * 32 + mi * 16 + row0;
            const int b = m >> 9, kk = m & 511;
            #pragma unroll
            for (int ni = 0; ni < 2; ++ni) {
                const int n = n0 + wc * 32 + ni * 16 + fr;
                s16x4 ev;
                #pragma unroll
                for (int j = 0; j < 4; ++j)
                    ev[j] = (short)f2bf(fminf(__builtin_amdgcn_exp2f(K2E * acc[mi][ni][j]), ECLAMP));
                *(s16x4*)&EbT[((size_t)b * 1024 + n) * 512 + kk] = ev;
            }
        }
    }
    #undef STAGE_MM
    #undef COMPUTE_MM
}

// ---------------------------------------------------------------------------
// fused scores+softmax (R16-proven config, best measured): block = (b, q-pair),
// 256 blocks x 1024 thr = kq(128) x hs(8). Packed f32x2, 4-way h-combine.
__global__ __launch_bounds__(1024, 4) void scores_softmax(
    const unsigned short* __restrict__ EbT, const float* __restrict__ Ea,
    const float* __restrict__ v,
    float* __restrict__ attn_out, short* __restrict__ attnb)
{
    __shared__ float4 s_eav[1024];       // {Ea_q0[h], Ea_q1[h], v[h], -} 16 KB
    __shared__ float  s_part[8][2][512]; // [hs][q][k] partials, 32 KB
    __shared__ float  s_red[16];
    const int t = threadIdx.x, bx = blockIdx.x;
    const int b = bx & 3;                // batch pinned per XCD pair
    const int q2 = bx >> 2;              // 0..63
    const int bq0 = b * 128 + q2 * 2;
    const int kq = t & 127;              // k-quad: k = 4kq..4kq+3 (full 512)
    const int hs = t >> 7;               // 8 h-slices of 128
    const int lane = t & 63, wid = t >> 6;

    s_eav[t] = make_float4(Ea[(size_t)(bq0 + 0) * 1024 + t],
                           Ea[(size_t)(bq0 + 1) * 1024 + t],
                           v[t], 0.f);
    __syncthreads();

    const int h0 = hs * 128;
    const uint2* up = (const uint2*)(EbT + ((size_t)(b * 1024 + h0)) * 512) + kq;
    f32x2 a0lo = {0.f, 0.f}, a0hi = {0.f, 0.f};   // q0: {k0,k1}, {k2,k3}
    f32x2 a1lo = {0.f, 0.f}, a1hi = {0.f, 0.f};   // q1
    const f32x2 one2 = {1.f, 1.f};

    #pragma unroll 2
    for (int hg = 0; hg < 32; ++hg) {    // 4-h groups (128 h per slice)
        const int hb = hg * 4;
        const uint2 r0 = up[(size_t)(hb + 0) * 128];   // h-stride = 128 uint2
        const uint2 r1 = up[(size_t)(hb + 1) * 128];
        const uint2 r2 = up[(size_t)(hb + 2) * 128];
        const uint2 r3 = up[(size_t)(hb + 3) * 128];
        const float4 ev0 = s_eav[h0 + hb + 0];
        const float4 ev1 = s_eav[h0 + hb + 1];
        const float4 ev2 = s_eav[h0 + hb + 2];
        const float4 ev3 = s_eav[h0 + hb + 3];
        #define UNPK(r) f32x2{__builtin_bit_cast(float, (r) << 16),            \
                              __builtin_bit_cast(float, (r) & 0xFFFF0000u)}
        const f32x2 b0lo = UNPK(r0.x), b0hi = UNPK(r0.y);
        const f32x2 b1lo = UNPK(r1.x), b1hi = UNPK(r1.y);
        const f32x2 b2lo = UNPK(r2.x), b2hi = UNPK(r2.y);
        const f32x2 b3lo = UNPK(r3.x), b3hi = UNPK(r3.y);
        #undef UNPK
        const f32x2 vv0 = {ev0.z, ev0.z}, vv1 = {ev1.z, ev1.z};
        const f32x2 vv2 = {ev2.z, ev2.z}, vv3 = {ev3.z, ev3.z};

        #define GRPPK(accv, EA0, EA1, EA2, EA3, B0, B1, B2, B3) do {            \
            const f32x2 u0 = B0 * EA0 + one2;                                   \
            const f32x2 u1 = B1 * EA1 + one2;                                   \
            const f32x2 u2 = B2 * EA2 + one2;                                   \
            const f32x2 u3 = B3 * EA3 + one2;                                   \
            const f32x2 d01 = u0 * u1, d23 = u2 * u3;                           \
            f32x2 n01 = vv0 * u1; n01 = vv1 * u0 + n01;                         \
            f32x2 n23 = vv2 * u3; n23 = vv3 * u2 + n23;                         \
            f32x2 n = n01 * d23; n = n23 * d01 + n;                             \
            const f32x2 den = d01 * d23;                                        \
            const f32x2 r = {__builtin_amdgcn_rcpf(den.x),                      \
                             __builtin_amdgcn_rcpf(den.y)};                     \
            accv = n * r + accv;                                                \
        } while (0)

        {   // q0
            const f32x2 e0 = {ev0.x, ev0.x}, e1 = {ev1.x, ev1.x};
            const f32x2 e2 = {ev2.x, ev2.x}, e3 = {ev3.x, ev3.x};
            GRPPK(a0lo, e0, e1, e2, e3, b0lo, b1lo, b2lo, b3lo);
            GRPPK(a0hi, e0, e1, e2, e3, b0hi, b1hi, b2hi, b3hi);
        }
        {   // q1
            const f32x2 e0 = {ev0.y, ev0.y}, e1 = {ev1.y, ev1.y};
            const f32x2 e2 = {ev2.y, ev2.y}, e3 = {ev3.y, ev3.y};
            GRPPK(a1lo, e0, e1, e2, e3, b0lo, b1lo, b2lo, b3lo);
            GRPPK(a1hi, e0, e1, e2, e3, b0hi, b1hi, b2hi, b3hi);
        }
        #undef GRPPK
    }
    *(f32x4*)&s_part[hs][0][kq * 4] = f32x4{a0lo.x, a0lo.y, a0hi.x, a0hi.y};
    *(f32x4*)&s_part[hs][1][kq * 4] = f32x4{a1lo.x, a1lo.y, a1hi.x, a1hi.y};
    __syncthreads();

    // combine + softmax: thread t -> (qq = t>>9, kk = t&511)
    const int kk = t & 511, qq = t >> 9;
    float z = 0.f;
    #pragma unroll
    for (int j = 0; j < 8; ++j) z += s_part[j][qq][kk];
    z *= -2.0f;

    // per-q max (waves 0-7 = q0, waves 8-15 = q1)
    float m = z;
    #pragma unroll
    for (int off = 32; off > 0; off >>= 1)
        m = fmaxf(m, __shfl_xor(m, off, 64));
    if (lane == 0) s_red[wid] = m;
    __syncthreads();
    float mx = s_red[qq * 8];
    #pragma unroll
    for (int w = 1; w < 8; ++w) mx = fmaxf(mx, s_red[qq * 8 + w]);
    const float p = __expf(z - mx);
    __syncthreads();   // WAR on s_red

    // per-q sum
    float sl = p;
    #pragma unroll
    for (int off = 32; off > 0; off >>= 1)
        sl += __shfl_xor(sl, off, 64);
    if (lane == 0) s_red[wid] = sl;
    __syncthreads();
    float s = 0.f;
    #pragma unroll
    for (int w = 0; w < 8; ++w) s += s_red[qq * 8 + w];

    const float a = p * (1.0f / s);
    attn_out[(size_t)(bq0 + qq) * 512 + kk] = a;
    attnb[(size_t)(bq0 + qq) * 512 + kk] = (short)f2bf(a);
}

// ---------------------------------------------------------------------------
// PV GEMM: outh[b][128][1024] = attnb[b][128][512] @ valT[b][1024][512]^T
// 64m x 32n tiles -> 256 blocks = 1 block/CU (4x CU coverage vs 64 blocks).
// K=512 (8 steps), dbuf LDS via global_load_lds, XOR-swizzled.
__global__ __launch_bounds__(256) void pv_gemm(
    const short* __restrict__ attnb, const short* __restrict__ valT,
    float* __restrict__ outh)
{
    __shared__ short ldsA[2][64][64];    // 16 KB
    __shared__ short ldsB[2][32][64];    // 8 KB
    const int t = threadIdx.x, bx = blockIdx.x;
    const int b = bx >> 6, mt = (bx >> 5) & 1, nt = bx & 31;
    const int m0 = mt * 64, n0 = nt * 32;
    const short* A = attnb + ((size_t)b * 128 + m0) * 512;             // [64][512]
    const short* B = valT + (size_t)b * 1024 * 512 + (size_t)n0 * 512; // [32][512]

    f32x4 acc[2];
    acc[0] = f32x4{0.f, 0.f, 0.f, 0.f};
    acc[1] = f32x4{0.f, 0.f, 0.f, 0.f};

    const int lane = t & 63, wid = t >> 6;
    const int wr = wid >> 1, wc = wid & 1;          // waves 2x2 over (32m,16n)
    const int fr = lane & 15, fko = (lane >> 4) * 16;

    #define STAGE_PV(buf, k0) do {                                              \
        _Pragma("unroll")                                                       \
        for (int it = 0; it < 2; ++it) {                                        \
            const int idx = it * 256 + t;                                       \
            const int row = idx >> 3, c16 = idx & 7;                            \
            const int sc = c16 ^ (row & 7);                                     \
            GLD16(A + (size_t)row * 512 + (k0) + sc * 8,                        \
                  &ldsA[buf][0][0] + idx * 8);                                  \
        }                                                                       \
        {                                                                       \
            const int idx = t;                                                  \
            const int row = idx >> 3, c16 = idx & 7;                            \
            const int sc = c16 ^ (row & 7);                                     \
            GLD16(B + (size_t)row * 512 + (k0) + sc * 8,                        \
                  &ldsB[buf][0][0] + idx * 8);                                  \
        }                                                                       \
    } while (0)

    #define COMPUTE_PV(buf) do {                                                \
        _Pragma("unroll")                                                       \
        for (int kk = 0; kk < 2; ++kk) {                                        \
            s16x8 af[2], bf1;                                                   \
            _Pragma("unroll")                                                   \
            for (int i = 0; i < 2; ++i) {                                       \
                const int rowA = wr * 32 + i * 16 + fr;                         \
                int offA = rowA * 128 + kk * 64 + fko; offA ^= (rowA & 7) << 4; \
                af[i] = *(const s16x8*)((const char*)&ldsA[buf][0][0] + offA);  \
            }                                                                   \
            {                                                                   \
                const int rowB = wc * 16 + fr;                                  \
                int offB = rowB * 128 + kk * 64 + fko; offB ^= (rowB & 7) << 4; \
                bf1 = *(const s16x8*)((const char*)&ldsB[buf][0][0] + offB);    \
            }                                                                   \
            _Pragma("unroll")                                                   \
            for (int mi = 0; mi < 2; ++mi)                                      \
                acc[mi] = __builtin_amdgcn_mfma_f32_16x16x32_bf16(              \
                              af[mi], bf1, acc[mi], 0, 0, 0);                   \
        }                                                                       \
    } while (0)

    STAGE_PV(0, 0);
    __syncthreads();
    int cur = 0;
    for (int s = 0; s < 7; ++s) {
        STAGE_PV(cur ^ 1, (s + 1) * 64);
        COMPUTE_PV(cur);
        __syncthreads();
        cur ^= 1;
    }
    COMPUTE_PV(cur);

    const int row0 = (lane >> 4) * 4;
    const int n = n0 + wc * 16 + fr;
    #pragma unroll
    for (int mi = 0; mi < 2; ++mi) {
        const int m = m0 + wr * 32 + mi * 16 + row0;
        #pragma unroll
        for (int j = 0; j < 4; ++j)
            outh[(size_t)(b * 128 + m + j) * 1024 + n] = acc[mi][j];
    }
    #undef STAGE_PV
    #undef COMPUTE_PV
}

extern "C" void kernel_launch(void* const* d_in, const int* in_sizes, int n_in,
                              void* d_out, int out_size, void* d_ws, size_t ws_size,
                              hipStream_t stream)
{
    const float* query = (const float*)d_in[0];
    const float* key   = (const float*)d_in[1];
    const float* value = (const float*)d_in[2];
    const float* Wq    = (const float*)d_in[3];
    const float* bq    = (const float*)d_in[4];
    const float* Wk    = (const float*)d_in[5];
    const float* v     = (const float*)d_in[6];
    float* out = (float*)d_out;

    // workspace layout (20 MB):
    char* w = (char*)d_ws;
    float*          ws_Ea  = (float*)w;                       // 2 MB
    unsigned short* ws_EbT = (unsigned short*)(w + (2u << 20)); // 4 MB (bf16)
    short* Qb     = (short*)(w + (6u << 20));                 // 1 MB
    short* Kb     = (short*)(w + (7u << 20));                 // 4 MB
    short* WqT    = (short*)(w + (11u << 20));                // 2 MB
    short* WkT    = (short*)(w + (13u << 20));                // 2 MB
    short* valT   = (short*)(w + (15u << 20));                // 4 MB
    short* attnb  = (short*)(w + (19u << 20));                // 0.5 MB

    float* out_h    = out;                                // [512][1024]
    float* out_attn = out + (size_t)NB * NTQ * NH;        // [512][512]

    prep_kernel   <<<dim3(1664), dim3(256),  0, stream>>>(query, key, Wq, Wk, value,
                                                          Qb, Kb, WqT, WkT, valT);
    mm_kernel     <<<dim3(640),  dim3(256),  0, stream>>>(Qb, Kb, WqT, WkT, bq, ws_Ea, ws_EbT);
    scores_softmax<<<dim3(256),  dim3(1024), 0, stream>>>(ws_EbT, ws_Ea, v, out_attn, attnb);
    pv_gemm       <<<dim3(256),  dim3(256),  0, stream>>>(attnb, valT, out_h);
}